// Round 1
// baseline (3353.041 us; speedup 1.0000x reference)
//
#include <hip/hip_runtime.h>

#define B_    64
#define CIN_  3
#define HW_   64
#define HID_  128
#define K_    1024
#define H1_   31      // after conv1 (stride2 k4)
#define H2_   30      // after conv2 (stride1 k2)
#define NROWS_ 57600  // B_*H2_*H2_
#define NELEM_ 7372800

// ---------------- conv1: x[64,3,64,64] -> relu -> z1[64,128,31,31] ----------
__global__ __launch_bounds__(256) void conv1_k(const float* __restrict__ x,
    const float* __restrict__ w, const float* __restrict__ bias,
    float* __restrict__ z1) {
  int blk = blockIdx.x, b = blk >> 7, co = blk & 127;     // grid = 64*128
  const float* wp = w + co * 48;                          // [co][ci][4][4]
  float wr[48];
  #pragma unroll
  for (int i = 0; i < 48; ++i) wr[i] = wp[i];             // uniform -> SGPRs
  const float* xb = x + (size_t)b * CIN_ * HW_ * HW_;
  float* zb = z1 + (size_t)blk * (H1_ * H1_);
  float bv = bias[co];
  for (int j = threadIdx.x; j < H1_ * H1_; j += 256) {
    int oh = j / H1_, ow = j % H1_;
    float acc = bv;
    #pragma unroll
    for (int ci = 0; ci < CIN_; ++ci) {
      const float* xp = xb + ci * HW_ * HW_ + (oh * 2) * HW_ + ow * 2;
      #pragma unroll
      for (int kh = 0; kh < 4; ++kh)
        #pragma unroll
        for (int kw = 0; kw < 4; ++kw)
          acc += xp[kh * HW_ + kw] * wr[ci * 16 + kh * 4 + kw];
    }
    zb[j] = fmaxf(acc, 0.f);
  }
}

// ---------------- conv2: z1 -> relu -> z[64,128,30,30] ----------------------
__global__ __launch_bounds__(256) void conv2_k(const float* __restrict__ z1,
    const float* __restrict__ w, const float* __restrict__ bias,
    float* __restrict__ z) {
  int blk = blockIdx.x, b = blk >> 7, co = blk & 127;     // grid = 64*128
  const float* wp = w + (size_t)co * HID_ * 4;            // [co][ci][2][2]
  const float* zin = z1 + (size_t)b * HID_ * (H1_ * H1_);
  float* zo = z + (size_t)blk * (H2_ * H2_);
  float bv = bias[co];
  float acc0 = bv, acc1 = bv, acc2 = bv, acc3 = bv;
  int j0 = threadIdx.x, j1 = j0 + 256, j2 = j0 + 512, j3 = j0 + 768;
  bool a3 = j3 < 900;
  int b0 = (j0 / 30) * H1_ + (j0 % 30);
  int b1 = (j1 / 30) * H1_ + (j1 % 30);
  int b2 = (j2 / 30) * H1_ + (j2 % 30);
  int b3 = a3 ? (j3 / 30) * H1_ + (j3 % 30) : 0;
  for (int ci = 0; ci < HID_; ++ci) {
    float4 wv = *(const float4*)(wp + ci * 4);            // uniform s_load
    const float* zp = zin + ci * (H1_ * H1_);
    acc0 += zp[b0]*wv.x + zp[b0+1]*wv.y + zp[b0+H1_]*wv.z + zp[b0+H1_+1]*wv.w;
    acc1 += zp[b1]*wv.x + zp[b1+1]*wv.y + zp[b1+H1_]*wv.z + zp[b1+H1_+1]*wv.w;
    acc2 += zp[b2]*wv.x + zp[b2+1]*wv.y + zp[b2+H1_]*wv.z + zp[b2+H1_+1]*wv.w;
    acc3 += zp[b3]*wv.x + zp[b3+1]*wv.y + zp[b3+H1_]*wv.z + zp[b3+H1_+1]*wv.w;
  }
  zo[j0] = fmaxf(acc0, 0.f);
  zo[j1] = fmaxf(acc1, 0.f);
  zo[j2] = fmaxf(acc2, 0.f);
  if (a3) zo[j3] = fmaxf(acc3, 0.f);
}

// ---------------- prep: codebook norms, zero hist/sse -----------------------
__global__ __launch_bounds__(256) void prep_k(const float* __restrict__ cb,
    float* __restrict__ cnorm, unsigned* __restrict__ hist,
    float* __restrict__ sse) {
  int k = blockIdx.x * 256 + threadIdx.x;
  if (k < K_) {
    float s0 = 0.f;
    #pragma unroll 4
    for (int d = 0; d < HID_; ++d) { float v = cb[k * HID_ + d]; s0 += v * v; }
    cnorm[k] = s0;
    hist[k] = 0u;
  }
  if (k == 0 && blockIdx.x == 0) *sse = 0.f;
}

__global__ __launch_bounds__(256) void zero_k(float4* __restrict__ p, int n4) {
  int i = blockIdx.x * 256 + threadIdx.x;
  if (i < n4) p[i] = make_float4(0.f, 0.f, 0.f, 0.f);
}

// ---------------- VQ: argmin over 1024 codes, scatter quant (padded), SSE ---
// flat row n = z[n*128 .. n*128+127] (raw C-order; rows cross channel bounds)
__global__ __launch_bounds__(256) void vq_k(const float* __restrict__ z,
    const float* __restrict__ cb, const float* __restrict__ cnorm,
    float* __restrict__ qp, unsigned* __restrict__ hist,
    float* __restrict__ sse) {
  int n = blockIdx.x * 256 + threadIdx.x;                 // 225*256 = 57600
  float r[HID_];
  {
    const float4* zr = (const float4*)(z + (size_t)n * HID_);
    #pragma unroll
    for (int i = 0; i < HID_ / 4; ++i) {
      float4 v = zr[i];
      r[4*i] = v.x; r[4*i+1] = v.y; r[4*i+2] = v.z; r[4*i+3] = v.w;
    }
  }
  float best = 3.4e38f; int bidx = 0;
  for (int k = 0; k < K_; ++k) {
    const float* cp = cb + (size_t)k * HID_;              // uniform -> s_load
    float d0 = 0.f, d1 = 0.f, d2 = 0.f, d3 = 0.f;
    #pragma unroll
    for (int d = 0; d < HID_; d += 4) {
      d0 += r[d]   * cp[d];
      d1 += r[d+1] * cp[d+1];
      d2 += r[d+2] * cp[d+2];
      d3 += r[d+3] * cp[d+3];
    }
    float dist = cnorm[k] - 2.f * ((d0 + d1) + (d2 + d3)); // argmin-equivalent
    if (dist < best) { best = dist; bidx = k; }            // strict < : first idx
  }
  // scatter quantized row into zero-padded [b][c][32][32]; accumulate SSE
  int f0 = n * HID_;
  int b  = f0 / (HID_ * 900);
  int rem = f0 % (HID_ * 900);
  int c = rem / 900;
  int s = rem % 900;
  const float* cp = cb + (size_t)bidx * HID_;
  float se = 0.f;
  #pragma unroll
  for (int d = 0; d < HID_; ++d) {
    float q = cp[d];
    int h = s / 30, ww = s - h * 30;
    qp[(((size_t)(b * HID_ + c)) << 10) + ((h + 1) << 5) + (ww + 1)] = q;
    float df = q - r[d];
    se += df * df;
    if (++s == 900) { s = 0; ++c; }
  }
  atomicAdd(&hist[bidx], 1u);
  __shared__ float red[256];
  red[threadIdx.x] = se;
  __syncthreads();
  #pragma unroll
  for (int t = 128; t > 0; t >>= 1) {
    if (threadIdx.x < t) red[threadIdx.x] += red[threadIdx.x + t];
    __syncthreads();
  }
  if (threadIdx.x == 0) atomicAdd(sse, red[0]);
}

// ---------------- convT1: qp[64,128,32,32] -> relu -> yp[64,128,33,33] ------
// y[oh][ow] = sum_ci ( q[oh][ow]w11 + q[oh][ow-1... ] ) via padded reads
__global__ __launch_bounds__(256) void convt1_k(const float* __restrict__ qp,
    const float* __restrict__ w, const float* __restrict__ bias,
    float* __restrict__ yp) {
  int blk = blockIdx.x, b = blk >> 7, co = blk & 127;     // grid = 64*128
  const float* qb = qp + ((size_t)(b * HID_) << 10);
  float* yb = yp + (size_t)blk * 1089;
  float bv = bias[co];
  float acc0 = bv, acc1 = bv, acc2 = bv, acc3 = bv;
  int j0 = threadIdx.x, j1 = j0 + 256, j2 = j0 + 512, j3 = j0 + 768;
  bool a3 = j3 < 961;
  int b0 = (j0 / 31) * 32 + (j0 % 31);
  int b1 = (j1 / 31) * 32 + (j1 % 31);
  int b2 = (j2 / 31) * 32 + (j2 % 31);
  int b3 = a3 ? (j3 / 31) * 32 + (j3 % 31) : 0;
  for (int ci = 0; ci < HID_; ++ci) {
    // dec_w1 layout [ci][co][kh][kw]; (w00,w01,w10,w11) = wv.(x,y,z,w)
    float4 wv = *(const float4*)(w + (((size_t)ci * HID_ + co) << 2));
    const float* qq = qb + (ci << 10);
    acc0 += qq[b0+33]*wv.x + qq[b0+32]*wv.y + qq[b0+1]*wv.z + qq[b0]*wv.w;
    acc1 += qq[b1+33]*wv.x + qq[b1+32]*wv.y + qq[b1+1]*wv.z + qq[b1]*wv.w;
    acc2 += qq[b2+33]*wv.x + qq[b2+32]*wv.y + qq[b2+1]*wv.z + qq[b2]*wv.w;
    acc3 += qq[b3+33]*wv.x + qq[b3+32]*wv.y + qq[b3+1]*wv.z + qq[b3]*wv.w;
  }
  {
    int oh = j0 / 31, ow = j0 % 31; yb[(oh+1)*33 + ow + 1] = fmaxf(acc0, 0.f);
  }
  { int oh = j1 / 31, ow = j1 % 31; yb[(oh+1)*33 + ow + 1] = fmaxf(acc1, 0.f); }
  { int oh = j2 / 31, ow = j2 % 31; yb[(oh+1)*33 + ow + 1] = fmaxf(acc2, 0.f); }
  if (a3) { int oh = j3 / 31, ow = j3 % 31; yb[(oh+1)*33 + ow + 1] = fmaxf(acc3, 0.f); }
}

// ---------------- convT2: yp[64,128,33,33] -> x_recon[64,3,64,64] -----------
__global__ __launch_bounds__(256) void convt2_k(const float* __restrict__ yp,
    const float* __restrict__ w, const float* __restrict__ bias,
    float* __restrict__ out) {
  int bc = blockIdx.x;                      // b*3 + co, 0..191
  int co = bc % 3, b = bc / 3;
  int j = blockIdx.y * 256 + threadIdx.x;   // 0..4095
  int oh = j >> 6, ow = j & 63;
  int r1 = (oh >> 1) + 1, c1 = (ow >> 1) + 1;
  int base = r1 * 33 + c1;
  int widx = co * 16 + ((oh & 1) << 2) + (ow & 1);  // dec_w2 [ci][co][4][4]
  const float* yb = yp + (size_t)b * HID_ * 1089;
  float acc = bias[co];
  for (int ci = 0; ci < HID_; ++ci) {
    const float* yr = yb + ci * 1089;
    const float* wp = w + ci * 48 + widx;
    acc += yr[base]      * wp[0]           // tap (kh0,   kw0)
         + yr[base - 1]  * wp[2]           // tap (kh0,   kw0+2)
         + yr[base - 33] * wp[8]           // tap (kh0+2, kw0)
         + yr[base - 34] * wp[10];         // tap (kh0+2, kw0+2)
  }
  out[(size_t)bc * 4096 + j] = acc;
}

// ---------------- finalize: loss + perplexity -------------------------------
__global__ __launch_bounds__(256) void fin_k(const unsigned* __restrict__ hist,
    const float* __restrict__ sse, float* __restrict__ out) {
  __shared__ float red[256];
  float e = 0.f;
  for (int k = threadIdx.x; k < K_; k += 256) {
    float p = (float)hist[k] * (1.0f / (float)NROWS_);
    e += p * logf(p + 1e-10f);
  }
  red[threadIdx.x] = e;
  __syncthreads();
  #pragma unroll
  for (int t = 128; t > 0; t >>= 1) {
    if (threadIdx.x < t) red[threadIdx.x] += red[threadIdx.x + t];
    __syncthreads();
  }
  if (threadIdx.x == 0) {
    out[786432] = 1.25f * (*sse) * (1.0f / (float)NELEM_);  // q_lat + 0.25*e_lat
    out[786433] = expf(-red[0]);
  }
}

extern "C" void kernel_launch(void* const* d_in, const int* in_sizes, int n_in,
                              void* d_out, int out_size, void* d_ws,
                              size_t ws_size, hipStream_t stream) {
  (void)in_sizes; (void)n_in; (void)out_size; (void)ws_size;
  const float* x   = (const float*)d_in[0];
  const float* ew1 = (const float*)d_in[1];
  const float* eb1 = (const float*)d_in[2];
  const float* ew2 = (const float*)d_in[3];
  const float* eb2 = (const float*)d_in[4];
  const float* cb  = (const float*)d_in[5];
  const float* dw1 = (const float*)d_in[6];
  const float* db1 = (const float*)d_in[7];
  const float* dw2 = (const float*)d_in[8];
  const float* db2 = (const float*)d_in[9];
  float* out = (float*)d_out;
  char* ws = (char*)d_ws;

  // workspace layout (~98.7 MB):
  //   [0, 35,684,352)            z1 (31.49 MB, dead after conv2) then yp (35.68 MB)
  //   [35,684,352, 65,175,552)   z  (29.49 MB)
  //   [65,175,552, 98,729,984)   qp (padded quantized, 33.55 MB)
  //   then hist (4 KB), cnorm (4 KB), sse (4 B)
  float*    z1    = (float*)(ws);
  float*    yp    = (float*)(ws);
  float*    z     = (float*)(ws + 35684352);
  float*    qp    = (float*)(ws + 35684352 + 29491200);
  unsigned* hist  = (unsigned*)(ws + 35684352 + 29491200 + 33554432);
  float*    cnorm = (float*)(ws + 35684352 + 29491200 + 33554432 + 4096);
  float*    sse   = (float*)(ws + 35684352 + 29491200 + 33554432 + 8192);

  conv1_k<<<dim3(B_ * HID_), dim3(256), 0, stream>>>(x, ew1, eb1, z1);
  conv2_k<<<dim3(B_ * HID_), dim3(256), 0, stream>>>(z1, ew2, eb2, z);
  prep_k<<<dim3(4), dim3(256), 0, stream>>>(cb, cnorm, hist, sse);
  zero_k<<<dim3(8192), dim3(256), 0, stream>>>((float4*)qp, 2097152);   // 32^2 planes
  vq_k<<<dim3(225), dim3(256), 0, stream>>>(z, cb, cnorm, qp, hist, sse);
  zero_k<<<dim3(8713), dim3(256), 0, stream>>>((float4*)yp, 2230272);   // 33^2 planes
  convt1_k<<<dim3(B_ * HID_), dim3(256), 0, stream>>>(qp, dw1, db1, yp);
  convt2_k<<<dim3(192, 16), dim3(256), 0, stream>>>(yp, dw2, db2, out);
  fin_k<<<dim3(1), dim3(256), 0, stream>>>(hist, sse, out);
}

// Round 2
// 2378.340 us; speedup vs baseline: 1.4098x; 1.4098x over previous
//
#include <hip/hip_runtime.h>

#define B_    64
#define CIN_  3
#define HW_   64
#define HID_  128
#define K_    1024
#define H1_   31      // after conv1 (stride2 k4)
#define H2_   30      // after conv2 (stride1 k2)
#define NROWS_ 57600  // B_*H2_*H2_
#define NELEM_ 7372800

// ---------------- conv1: x[64,3,64,64] -> relu -> z1[64,128,31,31] ----------
__global__ __launch_bounds__(256) void conv1_k(const float* __restrict__ x,
    const float* __restrict__ w, const float* __restrict__ bias,
    float* __restrict__ z1) {
  int blk = blockIdx.x, b = blk >> 7, co = blk & 127;     // grid = 64*128
  const float* wp = w + co * 48;                          // [co][ci][4][4]
  float wr[48];
  #pragma unroll
  for (int i = 0; i < 48; ++i) wr[i] = wp[i];             // uniform -> SGPRs
  const float* xb = x + (size_t)b * CIN_ * HW_ * HW_;
  float* zb = z1 + (size_t)blk * (H1_ * H1_);
  float bv = bias[co];
  for (int j = threadIdx.x; j < H1_ * H1_; j += 256) {
    int oh = j / H1_, ow = j % H1_;
    float acc = bv;
    #pragma unroll
    for (int ci = 0; ci < CIN_; ++ci) {
      const float* xp = xb + ci * HW_ * HW_ + (oh * 2) * HW_ + ow * 2;
      #pragma unroll
      for (int kh = 0; kh < 4; ++kh)
        #pragma unroll
        for (int kw = 0; kw < 4; ++kw)
          acc += xp[kh * HW_ + kw] * wr[ci * 16 + kh * 4 + kw];
    }
    zb[j] = fmaxf(acc, 0.f);
  }
}

// ---------------- conv2: z1 -> relu -> z[64,128,30,30] ----------------------
__global__ __launch_bounds__(256) void conv2_k(const float* __restrict__ z1,
    const float* __restrict__ w, const float* __restrict__ bias,
    float* __restrict__ z) {
  int blk = blockIdx.x, b = blk >> 7, co = blk & 127;     // grid = 64*128
  const float* wp = w + (size_t)co * HID_ * 4;            // [co][ci][2][2]
  const float* zin = z1 + (size_t)b * HID_ * (H1_ * H1_);
  float* zo = z + (size_t)blk * (H2_ * H2_);
  float bv = bias[co];
  float acc0 = bv, acc1 = bv, acc2 = bv, acc3 = bv;
  int j0 = threadIdx.x, j1 = j0 + 256, j2 = j0 + 512, j3 = j0 + 768;
  bool a3 = j3 < 900;
  int b0 = (j0 / 30) * H1_ + (j0 % 30);
  int b1 = (j1 / 30) * H1_ + (j1 % 30);
  int b2 = (j2 / 30) * H1_ + (j2 % 30);
  int b3 = a3 ? (j3 / 30) * H1_ + (j3 % 30) : 0;
  for (int ci = 0; ci < HID_; ++ci) {
    float4 wv = *(const float4*)(wp + ci * 4);            // uniform s_load
    const float* zp = zin + ci * (H1_ * H1_);
    acc0 += zp[b0]*wv.x + zp[b0+1]*wv.y + zp[b0+H1_]*wv.z + zp[b0+H1_+1]*wv.w;
    acc1 += zp[b1]*wv.x + zp[b1+1]*wv.y + zp[b1+H1_]*wv.z + zp[b1+H1_+1]*wv.w;
    acc2 += zp[b2]*wv.x + zp[b2+1]*wv.y + zp[b2+H1_]*wv.z + zp[b2+H1_+1]*wv.w;
    acc3 += zp[b3]*wv.x + zp[b3+1]*wv.y + zp[b3+H1_]*wv.z + zp[b3+H1_+1]*wv.w;
  }
  zo[j0] = fmaxf(acc0, 0.f);
  zo[j1] = fmaxf(acc1, 0.f);
  zo[j2] = fmaxf(acc2, 0.f);
  if (a3) zo[j3] = fmaxf(acc3, 0.f);
}

// ---------------- prep: codebook norms, zero hist/sse -----------------------
__global__ __launch_bounds__(256) void prep_k(const float* __restrict__ cb,
    float* __restrict__ cnorm, unsigned* __restrict__ hist,
    float* __restrict__ sse) {
  int k = blockIdx.x * 256 + threadIdx.x;
  if (k < K_) {
    float s0 = 0.f;
    #pragma unroll 4
    for (int d = 0; d < HID_; ++d) { float v = cb[k * HID_ + d]; s0 += v * v; }
    cnorm[k] = s0;
    hist[k] = 0u;
  }
  if (k == 0 && blockIdx.x == 0) *sse = 0.f;
}

__global__ __launch_bounds__(256) void zero_k(float4* __restrict__ p, int n4) {
  int i = blockIdx.x * 256 + threadIdx.x;
  if (i < n4) p[i] = make_float4(0.f, 0.f, 0.f, 0.f);
}

// ---------------- transpose: in[N][128] -> out[128][N], N % 64 == 0 ---------
__global__ __launch_bounds__(256) void tr_k(const float* __restrict__ in,
    float* __restrict__ out, int N) {
  __shared__ float t[64 * 133];
  int n0 = blockIdx.x * 64;
  int tid = threadIdx.x;
  const float4* in4 = (const float4*)in;
  #pragma unroll
  for (int s = 0; s < 8; ++s) {
    int flat = s * 256 + tid;          // 0..2047 float4s of the 64x128 tile
    int r = flat >> 5, c4 = flat & 31;
    float4 v = in4[n0 * 32 + flat];    // coalesced
    float* p = &t[r * 133 + c4 * 4];
    p[0] = v.x; p[1] = v.y; p[2] = v.z; p[3] = v.w;
  }
  __syncthreads();
  int w = tid >> 6, n_off = tid & 63;  // wave-uniform d, coalesced n
  #pragma unroll
  for (int s = 0; s < 32; ++s) {
    int d = s * 4 + w;
    out[d * N + n0 + n_off] = t[n_off * 133 + d];
  }
}

// ---------------- VQ phase 1: tiled GEMM-argmin over a 128-code chunk -------
// grid (8 chunks, 450 row-tiles) x 256 thr; 8x8 micro-tile per thread.
// dist = cnorm[k] - 2*dot (|z|^2 dropped: argmin-equivalent, matches r1).
__global__ __launch_bounds__(256, 2) void vq1_k(const float* __restrict__ zt,
    const float* __restrict__ cbt, const float* __restrict__ cnorm,
    unsigned long long* __restrict__ partial) {
  __shared__ __align__(16) float cbs[128 * 128];   // 64 KB -> 2 blocks/CU
  int chunk = blockIdx.x;          // 0..7
  int n0 = blockIdx.y * 128;
  int k0 = chunk * 128;
  int tid = threadIdx.x;
  // stage cbT[0..127][k0..k0+127] with xor-swizzled 8-float groups
  {
    const float4* cbt4 = (const float4*)cbt;
    #pragma unroll
    for (int s = 0; s < 16; ++s) {
      int flat = s * 256 + tid;            // 0..4095
      int d = flat >> 5, c4 = flat & 31;
      float4 v = cbt4[d * 256 + (k0 >> 2) + c4];   // coalesced
      int pg = (c4 >> 1) ^ (d & 15);
      *(float4*)&cbs[d * 128 + pg * 8 + (c4 & 1) * 4] = v;
    }
  }
  __syncthreads();
  int rg = tid & 15, cg = tid >> 4;        // 16 row-groups x 16 code-groups
  float acc[8][8];
  #pragma unroll
  for (int i = 0; i < 8; ++i)
    #pragma unroll
    for (int j = 0; j < 8; ++j) acc[i][j] = 0.f;
  const float4* zt4 = (const float4*)zt;
  int zbase = (n0 >> 2) + rg * 2;
  #pragma unroll 2
  for (int d = 0; d < 128; ++d) {
    float4 a0 = zt4[d * 14400 + zbase];            // rows (global, coalesced)
    float4 a1 = zt4[d * 14400 + zbase + 1];
    const float4* cp = (const float4*)&cbs[d * 128 + (cg ^ (d & 15)) * 8];
    float4 b0 = cp[0], b1 = cp[1];                 // LDS broadcast, no conflict
    float r_[8] = {a0.x, a0.y, a0.z, a0.w, a1.x, a1.y, a1.z, a1.w};
    float c_[8] = {b0.x, b0.y, b0.z, b0.w, b1.x, b1.y, b1.z, b1.w};
    #pragma unroll
    for (int i = 0; i < 8; ++i)
      #pragma unroll
      for (int j = 0; j < 8; ++j)
        acc[i][j] += r_[i] * c_[j];
  }
  float cn[8];
  {
    const float4* cn4 = (const float4*)cnorm;
    float4 c0 = cn4[(k0 >> 2) + cg * 2];
    float4 c1 = cn4[(k0 >> 2) + cg * 2 + 1];
    cn[0] = c0.x; cn[1] = c0.y; cn[2] = c0.z; cn[3] = c0.w;
    cn[4] = c1.x; cn[5] = c1.y; cn[6] = c1.z; cn[7] = c1.w;
  }
  __syncthreads();                                  // cbs reads done; reuse LDS
  unsigned long long* red = (unsigned long long*)cbs;
  #pragma unroll
  for (int i = 0; i < 8; ++i) {
    unsigned long long best = ~0ull;
    #pragma unroll
    for (int j = 0; j < 8; ++j) {
      float dist = cn[j] - 2.f * acc[i][j];
      unsigned u = __float_as_uint(dist);
      u = (u & 0x80000000u) ? ~u : (u | 0x80000000u);  // monotone map
      unsigned long long p =
          ((unsigned long long)u << 32) | (unsigned)(k0 + cg * 8 + j);
      if (p < best) best = p;                       // tie -> smaller k
    }
    red[(rg * 8 + i) * 16 + cg] = best;
  }
  __syncthreads();
  if (tid < 128) {
    unsigned long long best = ~0ull;
    #pragma unroll
    for (int c = 0; c < 16; ++c) {
      unsigned long long p = red[tid * 16 + c];
      if (p < best) best = p;
    }
    partial[(size_t)(n0 + tid) * 8 + chunk] = best;
  }
}

// ---------------- VQ phase 2: reduce 8 chunk candidates per row -------------
__global__ __launch_bounds__(256) void vq2_k(
    const unsigned long long* __restrict__ partial, int* __restrict__ idxArr) {
  int n = blockIdx.x * 256 + threadIdx.x;           // 225 blocks
  unsigned long long best = ~0ull;
  #pragma unroll
  for (int c = 0; c < 8; ++c) {
    unsigned long long p = partial[(size_t)n * 8 + c];
    if (p < best) best = p;
  }
  idxArr[n] = (int)(best & 0xffffffffu);
}

// ---------------- VQ phase 3: scatter quantized (padded) + SSE + hist -------
__global__ __launch_bounds__(256) void vq3_k(const float* __restrict__ z,
    const float* __restrict__ cb, const int* __restrict__ idxArr,
    float* __restrict__ qp, unsigned* __restrict__ hist,
    float* __restrict__ sse) {
  int n = blockIdx.x * 256 + threadIdx.x;           // 225 blocks
  int bidx = idxArr[n];
  int f0 = n * 128;
  int b = f0 / 115200, rem = f0 % 115200;
  int c = rem / 900, s = rem % 900;
  const float4* z4 = (const float4*)z;
  const float4* cb4 = (const float4*)cb;
  float se = 0.f;
  for (int q4 = 0; q4 < 32; ++q4) {
    float4 zv = z4[n * 32 + q4];
    float4 cv = cb4[bidx * 32 + q4];
    float qe[4] = {cv.x, cv.y, cv.z, cv.w};
    float ze[4] = {zv.x, zv.y, zv.z, zv.w};
    #pragma unroll
    for (int e = 0; e < 4; ++e) {
      int h = s / 30, ww = s - h * 30;
      qp[(((size_t)(b * HID_ + c)) << 10) + ((h + 1) << 5) + (ww + 1)] = qe[e];
      float df = qe[e] - ze[e];
      se += df * df;
      if (++s == 900) { s = 0; ++c; }
    }
  }
  atomicAdd(&hist[bidx], 1u);
  __shared__ float red[256];
  red[threadIdx.x] = se;
  __syncthreads();
  #pragma unroll
  for (int t = 128; t > 0; t >>= 1) {
    if (threadIdx.x < t) red[threadIdx.x] += red[threadIdx.x + t];
    __syncthreads();
  }
  if (threadIdx.x == 0) atomicAdd(sse, red[0]);
}

// ---------------- convT1: qp[64,128,32,32] -> relu -> yp[64,128,33,33] ------
__global__ __launch_bounds__(256) void convt1_k(const float* __restrict__ qp,
    const float* __restrict__ w, const float* __restrict__ bias,
    float* __restrict__ yp) {
  int blk = blockIdx.x, b = blk >> 7, co = blk & 127;     // grid = 64*128
  const float* qb = qp + ((size_t)(b * HID_) << 10);
  float* yb = yp + (size_t)blk * 1089;
  float bv = bias[co];
  float acc0 = bv, acc1 = bv, acc2 = bv, acc3 = bv;
  int j0 = threadIdx.x, j1 = j0 + 256, j2 = j0 + 512, j3 = j0 + 768;
  bool a3 = j3 < 961;
  int b0 = (j0 / 31) * 32 + (j0 % 31);
  int b1 = (j1 / 31) * 32 + (j1 % 31);
  int b2 = (j2 / 31) * 32 + (j2 % 31);
  int b3 = a3 ? (j3 / 31) * 32 + (j3 % 31) : 0;
  for (int ci = 0; ci < HID_; ++ci) {
    float4 wv = *(const float4*)(w + (((size_t)ci * HID_ + co) << 2));
    const float* qq = qb + (ci << 10);
    acc0 += qq[b0+33]*wv.x + qq[b0+32]*wv.y + qq[b0+1]*wv.z + qq[b0]*wv.w;
    acc1 += qq[b1+33]*wv.x + qq[b1+32]*wv.y + qq[b1+1]*wv.z + qq[b1]*wv.w;
    acc2 += qq[b2+33]*wv.x + qq[b2+32]*wv.y + qq[b2+1]*wv.z + qq[b2]*wv.w;
    acc3 += qq[b3+33]*wv.x + qq[b3+32]*wv.y + qq[b3+1]*wv.z + qq[b3]*wv.w;
  }
  { int oh = j0 / 31, ow = j0 % 31; yb[(oh+1)*33 + ow + 1] = fmaxf(acc0, 0.f); }
  { int oh = j1 / 31, ow = j1 % 31; yb[(oh+1)*33 + ow + 1] = fmaxf(acc1, 0.f); }
  { int oh = j2 / 31, ow = j2 % 31; yb[(oh+1)*33 + ow + 1] = fmaxf(acc2, 0.f); }
  if (a3) { int oh = j3 / 31, ow = j3 % 31; yb[(oh+1)*33 + ow + 1] = fmaxf(acc3, 0.f); }
}

// ---------------- convT2: yp[64,128,33,33] -> x_recon[64,3,64,64] -----------
__global__ __launch_bounds__(256) void convt2_k(const float* __restrict__ yp,
    const float* __restrict__ w, const float* __restrict__ bias,
    float* __restrict__ out) {
  int bc = blockIdx.x;                      // b*3 + co, 0..191
  int co = bc % 3, b = bc / 3;
  int j = blockIdx.y * 256 + threadIdx.x;   // 0..4095
  int oh = j >> 6, ow = j & 63;
  int r1 = (oh >> 1) + 1, c1 = (ow >> 1) + 1;
  int base = r1 * 33 + c1;
  int widx = co * 16 + ((oh & 1) << 2) + (ow & 1);  // dec_w2 [ci][co][4][4]
  const float* yb = yp + (size_t)b * HID_ * 1089;
  float acc = bias[co];
  for (int ci = 0; ci < HID_; ++ci) {
    const float* yr = yb + ci * 1089;
    const float* wp = w + ci * 48 + widx;
    acc += yr[base]      * wp[0]
         + yr[base - 1]  * wp[2]
         + yr[base - 33] * wp[8]
         + yr[base - 34] * wp[10];
  }
  out[(size_t)bc * 4096 + j] = acc;
}

// ---------------- finalize: loss + perplexity -------------------------------
__global__ __launch_bounds__(256) void fin_k(const unsigned* __restrict__ hist,
    const float* __restrict__ sse, float* __restrict__ out) {
  __shared__ float red[256];
  float e = 0.f;
  for (int k = threadIdx.x; k < K_; k += 256) {
    float p = (float)hist[k] * (1.0f / (float)NROWS_);
    e += p * logf(p + 1e-10f);
  }
  red[threadIdx.x] = e;
  __syncthreads();
  #pragma unroll
  for (int t = 128; t > 0; t >>= 1) {
    if (threadIdx.x < t) red[threadIdx.x] += red[threadIdx.x + t];
    __syncthreads();
  }
  if (threadIdx.x == 0) {
    out[786432] = 1.25f * (*sse) * (1.0f / (float)NELEM_);
    out[786433] = expf(-red[0]);
  }
}

extern "C" void kernel_launch(void* const* d_in, const int* in_sizes, int n_in,
                              void* d_out, int out_size, void* d_ws,
                              size_t ws_size, hipStream_t stream) {
  (void)in_sizes; (void)n_in; (void)out_size; (void)ws_size;
  const float* x   = (const float*)d_in[0];
  const float* ew1 = (const float*)d_in[1];
  const float* eb1 = (const float*)d_in[2];
  const float* ew2 = (const float*)d_in[3];
  const float* eb2 = (const float*)d_in[4];
  const float* cb  = (const float*)d_in[5];
  const float* dw1 = (const float*)d_in[6];
  const float* db1 = (const float*)d_in[7];
  const float* dw2 = (const float*)d_in[8];
  const float* db2 = (const float*)d_in[9];
  float* out = (float*)d_out;
  char* ws = (char*)d_ws;

  // ws layout (~98.74 MB, aliased by liveness):
  //  [0, 35,684,352)  z1 (dead after conv2) -> partial(3.69MB)+idx(0.23MB)
  //                   (dead after vq3) -> yp (35.68 MB)
  //  [35,684,352, 65,175,552)  z (29.49 MB, live through vq3)
  //  [65,175,552, 98,729,984)  zT (29.49MB)+cbT (0.5MB) (dead after vq1)
  //                            -> qp padded quantized (33.55 MB)
  //  [98,729,984 ..) hist 4KB | cnorm 4KB | sse
  float*    z1      = (float*)(ws);
  unsigned long long* partial = (unsigned long long*)(ws);
  int*      idxArr  = (int*)(ws + 3686400);
  float*    yp      = (float*)(ws);
  float*    z       = (float*)(ws + 35684352);
  float*    zT      = (float*)(ws + 65175552);
  float*    cbT     = (float*)(ws + 65175552 + 29491200);
  float*    qp      = (float*)(ws + 65175552);
  unsigned* hist    = (unsigned*)(ws + 98729984);
  float*    cnorm   = (float*)(ws + 98729984 + 4096);
  float*    sse     = (float*)(ws + 98729984 + 8192);

  conv1_k<<<dim3(B_ * HID_), dim3(256), 0, stream>>>(x, ew1, eb1, z1);
  conv2_k<<<dim3(B_ * HID_), dim3(256), 0, stream>>>(z1, ew2, eb2, z);
  prep_k<<<dim3(4), dim3(256), 0, stream>>>(cb, cnorm, hist, sse);
  tr_k<<<dim3(NROWS_ / 64), dim3(256), 0, stream>>>(z, zT, NROWS_);
  tr_k<<<dim3(K_ / 64), dim3(256), 0, stream>>>(cb, cbT, K_);
  vq1_k<<<dim3(8, 450), dim3(256), 0, stream>>>(zT, cbT, cnorm, partial);
  vq2_k<<<dim3(225), dim3(256), 0, stream>>>(partial, idxArr);
  zero_k<<<dim3(8192), dim3(256), 0, stream>>>((float4*)qp, 2097152);
  vq3_k<<<dim3(225), dim3(256), 0, stream>>>(z, cb, idxArr, qp, hist, sse);
  zero_k<<<dim3(8713), dim3(256), 0, stream>>>((float4*)yp, 2230272);
  convt1_k<<<dim3(B_ * HID_), dim3(256), 0, stream>>>(qp, dw1, db1, yp);
  convt2_k<<<dim3(192, 16), dim3(256), 0, stream>>>(yp, dw2, db2, out);
  fin_k<<<dim3(1), dim3(256), 0, stream>>>(hist, sse, out);
}

// Round 3
// 1066.976 us; speedup vs baseline: 3.1426x; 2.2290x over previous
//
#include <hip/hip_runtime.h>

#define B_    64
#define CIN_  3
#define HW_   64
#define HID_  128
#define K_    1024
#define H1_   31      // after conv1 (stride2 k4)
#define H2_   30      // after conv2 (stride1 k2)
#define NROWS_ 57600  // B_*H2_*H2_
#define NELEM_ 7372800

// ---------------- conv1: x[64,3,64,64] -> relu -> z1p[64,128,32,32] (padded)
__global__ __launch_bounds__(256) void conv1_k(const float* __restrict__ x,
    const float* __restrict__ w, const float* __restrict__ bias,
    float* __restrict__ z1p) {
  int blk = blockIdx.x, b = blk >> 7, co = blk & 127;     // grid = 64*128
  const float* wp = w + co * 48;                          // [co][ci][4][4]
  float wr[48];
  #pragma unroll
  for (int i = 0; i < 48; ++i) wr[i] = wp[i];             // uniform -> SGPRs
  const float* xb = x + (size_t)b * CIN_ * HW_ * HW_;
  float* zb = z1p + ((size_t)blk << 10);                  // 32x32 padded plane
  float bv = bias[co];
  for (int j = threadIdx.x; j < H1_ * H1_; j += 256) {
    int oh = j / H1_, ow = j % H1_;
    float acc = bv;
    #pragma unroll
    for (int ci = 0; ci < CIN_; ++ci) {
      const float* xp = xb + ci * HW_ * HW_ + (oh * 2) * HW_ + ow * 2;
      #pragma unroll
      for (int kh = 0; kh < 4; ++kh)
        #pragma unroll
        for (int kw = 0; kw < 4; ++kw)
          acc += xp[kh * HW_ + kw] * wr[ci * 16 + kh * 4 + kw];
    }
    zb[(oh << 5) + ow] = fmaxf(acc, 0.f);                 // pad never read
  }
}

// ---------------- conv2: z1p -> relu -> z[64,128,30,30] (compact) -----------
// block = (b, 16-co group); LDS-stage 8 ci planes/chunk, reuse across 16 co.
__global__ __launch_bounds__(256, 2) void conv2_k(const float* __restrict__ z1p,
    const float* __restrict__ w, const float* __restrict__ bias,
    float* __restrict__ z) {
  __shared__ __align__(16) float qs[8 * 1024];            // 32 KB
  int b = blockIdx.x >> 3, co0 = (blockIdx.x & 7) * 16;
  int tid = threadIdx.x;
  int j0 = tid, j1 = tid + 256, j2 = tid + 512, j3 = tid + 768;
  bool a3 = j3 < 900;
  int bp[4];
  bp[0] = (j0 / 30) * 32 + (j0 % 30);
  bp[1] = (j1 / 30) * 32 + (j1 % 30);
  bp[2] = (j2 / 30) * 32 + (j2 % 30);
  bp[3] = a3 ? (j3 / 30) * 32 + (j3 % 30) : 0;
  float acc[16][4];
  #pragma unroll
  for (int c = 0; c < 16; ++c)
    #pragma unroll
    for (int p = 0; p < 4; ++p) acc[c][p] = 0.f;
  const float4* src4 = (const float4*)(z1p + ((size_t)(b * HID_) << 10));
  const float4* w4 = (const float4*)w;                    // [co][ci] float4
  for (int ch = 0; ch < 16; ++ch) {
    __syncthreads();
    #pragma unroll
    for (int s = 0; s < 8; ++s) {
      int flat = s * 256 + tid;                           // f4 idx in 8 planes
      ((float4*)qs)[flat] = src4[(ch << 11) + flat];
    }
    __syncthreads();
    #pragma unroll
    for (int cl = 0; cl < 8; ++cl) {
      float tv[4][4];
      #pragma unroll
      for (int p = 0; p < 4; ++p) {
        const float* qq = &qs[cl * 1024 + bp[p]];
        tv[p][0] = qq[0]; tv[p][1] = qq[1]; tv[p][2] = qq[32]; tv[p][3] = qq[33];
      }
      #pragma unroll
      for (int c = 0; c < 16; ++c) {
        float4 wv = w4[(co0 + c) * HID_ + ch * 8 + cl];   // uniform s_load
        #pragma unroll
        for (int p = 0; p < 4; ++p)
          acc[c][p] += tv[p][0]*wv.x + tv[p][1]*wv.y + tv[p][2]*wv.z + tv[p][3]*wv.w;
      }
    }
  }
  #pragma unroll
  for (int c = 0; c < 16; ++c) {
    float bv = bias[co0 + c];
    float* zo = z + (size_t)(b * HID_ + co0 + c) * 900;
    zo[j0] = fmaxf(acc[c][0] + bv, 0.f);
    zo[j1] = fmaxf(acc[c][1] + bv, 0.f);
    zo[j2] = fmaxf(acc[c][2] + bv, 0.f);
    if (a3) zo[j3] = fmaxf(acc[c][3] + bv, 0.f);
  }
}

// ---------------- prep: codebook norms, zero hist/sse -----------------------
__global__ __launch_bounds__(256) void prep_k(const float* __restrict__ cb,
    float* __restrict__ cnorm, unsigned* __restrict__ hist,
    float* __restrict__ sse) {
  int k = blockIdx.x * 256 + threadIdx.x;
  if (k < K_) {
    float s0 = 0.f;
    #pragma unroll 4
    for (int d = 0; d < HID_; ++d) { float v = cb[k * HID_ + d]; s0 += v * v; }
    cnorm[k] = s0;
    hist[k] = 0u;
  }
  if (k == 0 && blockIdx.x == 0) *sse = 0.f;
}

__global__ __launch_bounds__(256) void zero_k(float4* __restrict__ p, int n4) {
  int i = blockIdx.x * 256 + threadIdx.x;
  if (i < n4) p[i] = make_float4(0.f, 0.f, 0.f, 0.f);
}

// ---------------- transpose: in[N][128] -> out[128][N], N % 64 == 0 ---------
__global__ __launch_bounds__(256) void tr_k(const float* __restrict__ in,
    float* __restrict__ out, int N) {
  __shared__ float t[64 * 133];
  int n0 = blockIdx.x * 64;
  int tid = threadIdx.x;
  const float4* in4 = (const float4*)in;
  #pragma unroll
  for (int s = 0; s < 8; ++s) {
    int flat = s * 256 + tid;          // 0..2047 float4s of the 64x128 tile
    int r = flat >> 5, c4 = flat & 31;
    float4 v = in4[n0 * 32 + flat];    // coalesced
    float* p = &t[r * 133 + c4 * 4];
    p[0] = v.x; p[1] = v.y; p[2] = v.z; p[3] = v.w;
  }
  __syncthreads();
  int w = tid >> 6, n_off = tid & 63;  // wave-uniform d, coalesced n
  #pragma unroll
  for (int s = 0; s < 32; ++s) {
    int d = s * 4 + w;
    out[d * N + n0 + n_off] = t[n_off * 133 + d];
  }
}

// ---------------- VQ phase 1: tiled GEMM-argmin over a 128-code chunk -------
__global__ __launch_bounds__(256, 2) void vq1_k(const float* __restrict__ zt,
    const float* __restrict__ cbt, const float* __restrict__ cnorm,
    unsigned long long* __restrict__ partial) {
  __shared__ __align__(16) float cbs[128 * 128];   // 64 KB -> 2 blocks/CU
  int chunk = blockIdx.x;          // 0..7
  int n0 = blockIdx.y * 128;
  int k0 = chunk * 128;
  int tid = threadIdx.x;
  {
    const float4* cbt4 = (const float4*)cbt;
    #pragma unroll
    for (int s = 0; s < 16; ++s) {
      int flat = s * 256 + tid;            // 0..4095
      int d = flat >> 5, c4 = flat & 31;
      float4 v = cbt4[d * 256 + (k0 >> 2) + c4];   // coalesced
      int pg = (c4 >> 1) ^ (d & 15);
      *(float4*)&cbs[d * 128 + pg * 8 + (c4 & 1) * 4] = v;
    }
  }
  __syncthreads();
  int rg = tid & 15, cg = tid >> 4;        // 16 row-groups x 16 code-groups
  float acc[8][8];
  #pragma unroll
  for (int i = 0; i < 8; ++i)
    #pragma unroll
    for (int j = 0; j < 8; ++j) acc[i][j] = 0.f;
  const float4* zt4 = (const float4*)zt;
  int zbase = (n0 >> 2) + rg * 2;
  #pragma unroll 2
  for (int d = 0; d < 128; ++d) {
    float4 a0 = zt4[d * 14400 + zbase];            // rows (global, coalesced)
    float4 a1 = zt4[d * 14400 + zbase + 1];
    const float4* cp = (const float4*)&cbs[d * 128 + (cg ^ (d & 15)) * 8];
    float4 b0 = cp[0], b1 = cp[1];                 // LDS broadcast, no conflict
    float r_[8] = {a0.x, a0.y, a0.z, a0.w, a1.x, a1.y, a1.z, a1.w};
    float c_[8] = {b0.x, b0.y, b0.z, b0.w, b1.x, b1.y, b1.z, b1.w};
    #pragma unroll
    for (int i = 0; i < 8; ++i)
      #pragma unroll
      for (int j = 0; j < 8; ++j)
        acc[i][j] += r_[i] * c_[j];
  }
  float cn[8];
  {
    const float4* cn4 = (const float4*)cnorm;
    float4 c0 = cn4[(k0 >> 2) + cg * 2];
    float4 c1 = cn4[(k0 >> 2) + cg * 2 + 1];
    cn[0] = c0.x; cn[1] = c0.y; cn[2] = c0.z; cn[3] = c0.w;
    cn[4] = c1.x; cn[5] = c1.y; cn[6] = c1.z; cn[7] = c1.w;
  }
  __syncthreads();                                  // cbs reads done; reuse LDS
  unsigned long long* red = (unsigned long long*)cbs;
  #pragma unroll
  for (int i = 0; i < 8; ++i) {
    unsigned long long best = ~0ull;
    #pragma unroll
    for (int j = 0; j < 8; ++j) {
      float dist = cn[j] - 2.f * acc[i][j];
      unsigned u = __float_as_uint(dist);
      u = (u & 0x80000000u) ? ~u : (u | 0x80000000u);  // monotone map
      unsigned long long p =
          ((unsigned long long)u << 32) | (unsigned)(k0 + cg * 8 + j);
      if (p < best) best = p;                       // tie -> smaller k
    }
    red[(rg * 8 + i) * 16 + cg] = best;
  }
  __syncthreads();
  if (tid < 128) {
    unsigned long long best = ~0ull;
    #pragma unroll
    for (int c = 0; c < 16; ++c) {
      unsigned long long p = red[tid * 16 + c];
      if (p < best) best = p;
    }
    partial[(size_t)(n0 + tid) * 8 + chunk] = best;
  }
}

// ---------------- VQ phase 2: reduce 8 chunk candidates per row -------------
__global__ __launch_bounds__(256) void vq2_k(
    const unsigned long long* __restrict__ partial, int* __restrict__ idxArr) {
  int n = blockIdx.x * 256 + threadIdx.x;           // 225 blocks
  unsigned long long best = ~0ull;
  #pragma unroll
  for (int c = 0; c < 8; ++c) {
    unsigned long long p = partial[(size_t)n * 8 + c];
    if (p < best) best = p;
  }
  idxArr[n] = (int)(best & 0xffffffffu);
}

// ---------------- VQ phase 3: scatter quantized (padded) + SSE + hist -------
__global__ __launch_bounds__(256) void vq3_k(const float* __restrict__ z,
    const float* __restrict__ cb, const int* __restrict__ idxArr,
    float* __restrict__ qp, unsigned* __restrict__ hist,
    float* __restrict__ sse) {
  int n = blockIdx.x * 256 + threadIdx.x;           // 225 blocks
  int bidx = idxArr[n];
  int f0 = n * 128;
  int b = f0 / 115200, rem = f0 % 115200;
  int c = rem / 900, s = rem % 900;
  const float4* z4 = (const float4*)z;
  const float4* cb4 = (const float4*)cb;
  float se = 0.f;
  for (int q4 = 0; q4 < 32; ++q4) {
    float4 zv = z4[n * 32 + q4];
    float4 cv = cb4[bidx * 32 + q4];
    float qe[4] = {cv.x, cv.y, cv.z, cv.w};
    float ze[4] = {zv.x, zv.y, zv.z, zv.w};
    #pragma unroll
    for (int e = 0; e < 4; ++e) {
      int h = s / 30, ww = s - h * 30;
      qp[(((size_t)(b * HID_ + c)) << 10) + ((h + 1) << 5) + (ww + 1)] = qe[e];
      float df = qe[e] - ze[e];
      se += df * df;
      if (++s == 900) { s = 0; ++c; }
    }
  }
  atomicAdd(&hist[bidx], 1u);
  __shared__ float red[256];
  red[threadIdx.x] = se;
  __syncthreads();
  #pragma unroll
  for (int t = 128; t > 0; t >>= 1) {
    if (threadIdx.x < t) red[threadIdx.x] += red[threadIdx.x + t];
    __syncthreads();
  }
  if (threadIdx.x == 0) atomicAdd(sse, red[0]);
}

// ---------------- convT1: qp[64,128,32,32] -> relu -> yp[64,128,33,33] ------
// block = (b, 16-co group); LDS-stage 8 ci planes/chunk, reuse across 16 co.
__global__ __launch_bounds__(256, 2) void convt1_k(const float* __restrict__ qp,
    const float* __restrict__ w, const float* __restrict__ bias,
    float* __restrict__ yp) {
  __shared__ __align__(16) float qs[8 * 1024];            // 32 KB
  int b = blockIdx.x >> 3, co0 = (blockIdx.x & 7) * 16;
  int tid = threadIdx.x;
  int j0 = tid, j1 = tid + 256, j2 = tid + 512, j3 = tid + 768;
  bool a3 = j3 < 961;
  int bp[4];
  bp[0] = (j0 / 31) * 32 + (j0 % 31);
  bp[1] = (j1 / 31) * 32 + (j1 % 31);
  bp[2] = (j2 / 31) * 32 + (j2 % 31);
  bp[3] = a3 ? (j3 / 31) * 32 + (j3 % 31) : 0;
  float acc[16][4];
  #pragma unroll
  for (int c = 0; c < 16; ++c)
    #pragma unroll
    for (int p = 0; p < 4; ++p) acc[c][p] = 0.f;
  const float4* src4 = (const float4*)(qp + ((size_t)(b * HID_) << 10));
  const float4* w4 = (const float4*)w;                    // [ci][co] float4
  for (int ch = 0; ch < 16; ++ch) {
    __syncthreads();
    #pragma unroll
    for (int s = 0; s < 8; ++s) {
      int flat = s * 256 + tid;
      ((float4*)qs)[flat] = src4[(ch << 11) + flat];
    }
    __syncthreads();
    #pragma unroll
    for (int cl = 0; cl < 8; ++cl) {
      float tv[4][4];
      #pragma unroll
      for (int p = 0; p < 4; ++p) {
        const float* qq = &qs[cl * 1024 + bp[p]];
        // taps match r2-verified math: +33 (w00), +32 (w01), +1 (w10), +0 (w11)
        tv[p][0] = qq[33]; tv[p][1] = qq[32]; tv[p][2] = qq[1]; tv[p][3] = qq[0];
      }
      #pragma unroll
      for (int c = 0; c < 16; ++c) {
        float4 wv = w4[(ch * 8 + cl) * HID_ + co0 + c];   // uniform s_load
        #pragma unroll
        for (int p = 0; p < 4; ++p)
          acc[c][p] += tv[p][0]*wv.x + tv[p][1]*wv.y + tv[p][2]*wv.z + tv[p][3]*wv.w;
      }
    }
  }
  int oh[4], ow[4];
  oh[0] = j0 / 31; ow[0] = j0 % 31;
  oh[1] = j1 / 31; ow[1] = j1 % 31;
  oh[2] = j2 / 31; ow[2] = j2 % 31;
  oh[3] = a3 ? j3 / 31 : 0; ow[3] = a3 ? j3 % 31 : 0;
  #pragma unroll
  for (int c = 0; c < 16; ++c) {
    float bv = bias[co0 + c];
    float* yb = yp + (size_t)(b * HID_ + co0 + c) * 1089;
    yb[(oh[0] + 1) * 33 + ow[0] + 1] = fmaxf(acc[c][0] + bv, 0.f);
    yb[(oh[1] + 1) * 33 + ow[1] + 1] = fmaxf(acc[c][1] + bv, 0.f);
    yb[(oh[2] + 1) * 33 + ow[2] + 1] = fmaxf(acc[c][2] + bv, 0.f);
    if (a3) yb[(oh[3] + 1) * 33 + ow[3] + 1] = fmaxf(acc[c][3] + bv, 0.f);
  }
}

// ---------------- convT2: yp[64,128,33,33] -> x_recon[64,3,64,64] -----------
// parity-uniform remap: (oh&1, ow&1) constant per block -> weight s_loads
__global__ __launch_bounds__(256) void convt2_k(const float* __restrict__ yp,
    const float* __restrict__ w, const float* __restrict__ bias,
    float* __restrict__ out) {
  int bc = blockIdx.x;                      // b*3 + co, 0..191
  int co = bc % 3, b = bc / 3;
  int yq = blockIdx.y;                      // 0..15
  int ph = (yq >> 1) & 1, pw = yq & 1, qg = yq >> 2;
  int i = qg * 256 + threadIdx.x;           // 0..1023 over 32x32 quadrant
  int qh = i >> 5, qw = i & 31;
  int oh = qh * 2 + ph, ow = qw * 2 + pw;
  int base = (qh + 1) * 33 + qw + 1;
  const float* yb = yp + (size_t)b * HID_ * 1089;
  const float* wp0 = w + co * 16 + ph * 4 + pw;   // + ci*48, block-uniform
  float acc = bias[co];
  for (int ci = 0; ci < HID_; ++ci) {
    const float* yr = yb + ci * 1089;
    const float* wp = wp0 + ci * 48;
    acc += yr[base]      * wp[0]
         + yr[base - 1]  * wp[2]
         + yr[base - 33] * wp[8]
         + yr[base - 34] * wp[10];
  }
  out[(size_t)bc * 4096 + oh * 64 + ow] = acc;
}

// ---------------- finalize: loss + perplexity -------------------------------
__global__ __launch_bounds__(256) void fin_k(const unsigned* __restrict__ hist,
    const float* __restrict__ sse, float* __restrict__ out) {
  __shared__ float red[256];
  float e = 0.f;
  for (int k = threadIdx.x; k < K_; k += 256) {
    float p = (float)hist[k] * (1.0f / (float)NROWS_);
    e += p * logf(p + 1e-10f);
  }
  red[threadIdx.x] = e;
  __syncthreads();
  #pragma unroll
  for (int t = 128; t > 0; t >>= 1) {
    if (threadIdx.x < t) red[threadIdx.x] += red[threadIdx.x + t];
    __syncthreads();
  }
  if (threadIdx.x == 0) {
    out[786432] = 1.25f * (*sse) * (1.0f / (float)NELEM_);
    out[786433] = expf(-red[0]);
  }
}

extern "C" void kernel_launch(void* const* d_in, const int* in_sizes, int n_in,
                              void* d_out, int out_size, void* d_ws,
                              size_t ws_size, hipStream_t stream) {
  (void)in_sizes; (void)n_in; (void)out_size; (void)ws_size;
  const float* x   = (const float*)d_in[0];
  const float* ew1 = (const float*)d_in[1];
  const float* eb1 = (const float*)d_in[2];
  const float* ew2 = (const float*)d_in[3];
  const float* eb2 = (const float*)d_in[4];
  const float* cb  = (const float*)d_in[5];
  const float* dw1 = (const float*)d_in[6];
  const float* db1 = (const float*)d_in[7];
  const float* dw2 = (const float*)d_in[8];
  const float* db2 = (const float*)d_in[9];
  float* out = (float*)d_out;
  char* ws = (char*)d_ws;

  // ws layout (~98.74 MB, aliased by liveness):
  //  [0, 35,684,352)  z1p padded (33.55 MB, dead after conv2)
  //                   -> partial(3.69MB)+idx(0.23MB) -> yp (35.68 MB)
  //  [35,684,352, 65,175,552)  z (29.49 MB, live through vq3)
  //  [65,175,552, 98,729,984)  zT (29.49MB)+cbT (0.5MB) (dead after vq1)
  //                            -> qp padded quantized (33.55 MB)
  //  [98,729,984 ..) hist 4KB | cnorm 4KB | sse
  float*    z1p     = (float*)(ws);
  unsigned long long* partial = (unsigned long long*)(ws);
  int*      idxArr  = (int*)(ws + 3686400);
  float*    yp      = (float*)(ws);
  float*    z       = (float*)(ws + 35684352);
  float*    zT      = (float*)(ws + 65175552);
  float*    cbT     = (float*)(ws + 65175552 + 29491200);
  float*    qp      = (float*)(ws + 65175552);
  unsigned* hist    = (unsigned*)(ws + 98729984);
  float*    cnorm   = (float*)(ws + 98729984 + 4096);
  float*    sse     = (float*)(ws + 98729984 + 8192);

  conv1_k<<<dim3(B_ * HID_), dim3(256), 0, stream>>>(x, ew1, eb1, z1p);
  conv2_k<<<dim3(B_ * 8), dim3(256), 0, stream>>>(z1p, ew2, eb2, z);
  prep_k<<<dim3(4), dim3(256), 0, stream>>>(cb, cnorm, hist, sse);
  tr_k<<<dim3(NROWS_ / 64), dim3(256), 0, stream>>>(z, zT, NROWS_);
  tr_k<<<dim3(K_ / 64), dim3(256), 0, stream>>>(cb, cbT, K_);
  vq1_k<<<dim3(8, 450), dim3(256), 0, stream>>>(zT, cbT, cnorm, partial);
  vq2_k<<<dim3(225), dim3(256), 0, stream>>>(partial, idxArr);
  zero_k<<<dim3(8192), dim3(256), 0, stream>>>((float4*)qp, 2097152);
  vq3_k<<<dim3(225), dim3(256), 0, stream>>>(z, cb, idxArr, qp, hist, sse);
  zero_k<<<dim3(8713), dim3(256), 0, stream>>>((float4*)yp, 2230272);
  convt1_k<<<dim3(B_ * 8), dim3(256), 0, stream>>>(qp, dw1, db1, yp);
  convt2_k<<<dim3(192, 16), dim3(256), 0, stream>>>(yp, dw2, db2, out);
  fin_k<<<dim3(1), dim3(256), 0, stream>>>(hist, sse, out);
}